// Round 7
// baseline (326.325 us; speedup 1.0000x reference)
//
#include <hip/hip_runtime.h>
#include <hip/hip_bf16.h>

#define PREFIX_N 20000
#define LEAF_N   50000
#define CH_N     100000
#define CCOL     256
#define GK       2048
#define GM       50000
#define BM       64
#define BKF      128                    /* K floats per step */
#define NST      (GK / BKF)             /* 16 steps */
#define TILES    ((GM + BM - 1) / BM)   /* 782 */
#define NCOPYB   512
#define COPYROWS 70000

typedef float  f32x4v __attribute__((ext_vector_type(4)));
typedef __bf16 bf16x8 __attribute__((ext_vector_type(8)));
typedef short  s16x8  __attribute__((ext_vector_type(8)));

static __device__ __forceinline__ unsigned pk2(float a, float b) {
  __hip_bfloat16 ha = __float2bfloat16(a);
  __hip_bfloat16 hb = __float2bfloat16(b);
  unsigned short sa = __builtin_bit_cast(unsigned short, ha);
  unsigned short sb = __builtin_bit_cast(unsigned short, hb);
  return (unsigned)sa | ((unsigned)sb << 16);
}
static __device__ __forceinline__ uint4 pack8(const float4& x, const float4& y) {
  uint4 r;
  r.x = pk2(x.x, x.y); r.y = pk2(x.z, x.w);
  r.z = pk2(y.x, y.y); r.w = pk2(y.z, y.w);
  return r;
}

// ---- prep: W fp32->bf16 (blocks 0..255) + leaf count (blocks 256..646) ---
__global__ __launch_bounds__(256) void prep_kernel(const float* __restrict__ W,
                                                   unsigned short* __restrict__ Wb,
                                                   const int* __restrict__ ch,
                                                   int* __restrict__ cnt) {
  if (blockIdx.x < 256) {
    int i = blockIdx.x * 256 + threadIdx.x;
    float4 a = ((const float4*)W)[i * 2];
    float4 b = ((const float4*)W)[i * 2 + 1];
    *(uint4*)&Wb[i * 8] = pack8(a, b);
  } else {
    int blk = blockIdx.x - 256;
    int gi = blk * 256 + threadIdx.x;
    int lm = (gi < CH_N && ch[gi] < 0) ? 1 : 0;
    unsigned long long mask = __ballot(lm);
    __shared__ int wsum[4];
    int lane = threadIdx.x & 63, w = threadIdx.x >> 6;
    if (lane == 0) wsum[w] = __popcll(mask);
    __syncthreads();
    if (threadIdx.x == 0) cnt[blk] = wsum[0] + wsum[1] + wsum[2] + wsum[3];
  }
}

__global__ __launch_bounds__(512) void scan_blocks(const int* __restrict__ cnt,
                                                   int* __restrict__ boff, int nb) {
  __shared__ int s[512];
  int t = threadIdx.x;
  int v = (t < nb) ? cnt[t] : 0;
  s[t] = v;
  __syncthreads();
  for (int d = 1; d < 512; d <<= 1) {
    int add = (t >= d) ? s[t - d] : 0;
    __syncthreads();
    s[t] += add;
    __syncthreads();
  }
  if (t < nb) boff[t] = s[t] - v;
}

__global__ __launch_bounds__(256) void rank_kernel(const int* __restrict__ ch,
                                                   const int* __restrict__ boff, int n,
                                                   int* __restrict__ rowof,
                                                   int* __restrict__ leafof) {
  int gi = blockIdx.x * 256 + threadIdx.x;
  int lane = threadIdx.x & 63, w = threadIdx.x >> 6;
  int lm = (gi < n && ch[gi] < 0) ? 1 : 0;
  unsigned long long mask = __ballot(lm);
  int lrank = __popcll(mask & ((1ull << lane) - 1ull));
  __shared__ int wcnt[4];
  if (lane == 63) wcnt[w] = lrank + lm;
  __syncthreads();
  int woff = 0;
  for (int i = 0; i < w; ++i) woff += wcnt[i];
  if (gi < n) {
    int rl = boff[blockIdx.x] + woff + lrank;
    if (lm) leafof[rl] = gi;
    else    rowof[gi - rl] = gi;
  }
}

// ---- main: GEMM tiles (blocks < TILES) + grid-stride row copies ----------
// GEMM: BM=64, BN=256(full), BK=128; 512 thr = 8 waves (2M x 4N), wave tile
// 32x64. A reg-staged (plain dwordx4, dist-2 prefetch) -> cvt bf16 ->
// XOR-swizzled LDS dbuf. ONE raw s_barrier per K-step, lgkmcnt(0) only —
// no vmcnt drain ever (no __syncthreads, no global_load_lds). B direct
// from L2-resident bf16 W.
__global__ __launch_bounds__(512, 4) void main_kernel(const float* __restrict__ x,
                                                      const float* __restrict__ A,
                                                      const unsigned short* __restrict__ Wb,
                                                      const int* __restrict__ rowof,
                                                      const int* __restrict__ leafof,
                                                      float* __restrict__ out) {
  __shared__ unsigned short Al[2][BM * BKF];   // bf16, swizzled 16B granules
  __shared__ int tgt[BM];

  const int tid  = threadIdx.x;
  const int lane = tid & 63;
  const int w    = tid >> 6;

  if (blockIdx.x >= TILES) {                      // ---- copy path ----
    int cb = blockIdx.x - TILES;
    for (int r0 = cb * 8; r0 < COPYROWS; r0 += NCOPYB * 8) {
      int j = r0 + w;
      if (j >= COPYROWS) break;
      const float* src;
      float* dst;
      if (j < PREFIX_N) {
        src = x + (size_t)j * CCOL;
        dst = out + (size_t)j * CCOL;
      } else {
        int r = j - PREFIX_N;
        src = x + (size_t)(PREFIX_N + r) * CCOL;
        dst = out + (size_t)(PREFIX_N + leafof[r]) * CCOL;
      }
      ((float4*)dst)[lane] = ((const float4*)src)[lane];
    }
    return;
  }

  // ---- GEMM path ----
  const int tile = blockIdx.x;
  const int wm   = w >> 2;             // 0..1 : M half
  const int wn   = w & 3;              // 0..3 : N quadrant
  const int lr   = lane & 15, lq = lane >> 4;

  if (tid < BM) {
    int m = tile * BM + tid;
    tgt[tid] = (m < GM) ? (PREFIX_N + rowof[m]) : -1;
  }

  // staging: thread -> row sr = tid>>3 (0..63), 16 fp32 at col (tid&7)*16
  const int sr = tid >> 3;
  const int sc = (tid & 7) * 16;
  int agr = tile * BM + sr;
  if (agr >= GM) agr = GM - 1;                    // clamp (stores predicated)
  const float* aptr = A + (size_t)agr * GK + sc;
  // two 16B-granule LDS slots, XOR-swizzled: phys = g ^ (row&15)
  const int g0  = (tid & 7) * 2;
  const int pw0 = sr * BKF + ((g0)     ^ (sr & 15)) * 8;   // short index
  const int pw1 = sr * BKF + ((g0 + 1) ^ (sr & 15)) * 8;

  // frag-read bases: rows wm*32 + fm*16 + lr  (row&15 == lr)
  const int ar0 = (wm * 32 + lr) * BKF;
  const int ar1 = ar0 + 16 * BKF;
  // B fragment base pointers (global; Wb 1MB, L2-resident)
  const unsigned short* bb[4];
#pragma unroll
  for (int fn = 0; fn < 4; ++fn)
    bb[fn] = Wb + (size_t)(wn * 64 + fn * 16 + lr) * GK + lq * 8;

  f32x4v acc[2][4] = {};

  float4 rP0, rP1, rP2, rP3, rQ0, rQ1, rQ2, rQ3;

#define LOADA(d0, d1, d2, d3, kc)                                            \
  { const float4* p_ = (const float4*)(aptr + (kc) * BKF);                   \
    d0 = p_[0]; d1 = p_[1]; d2 = p_[2]; d3 = p_[3]; }

#define STAGE(buf_, s0, s1, s2, s3)                                          \
  { *(uint4*)&Al[(buf_)][pw0] = pack8(s0, s1);                               \
    *(uint4*)&Al[(buf_)][pw1] = pack8(s2, s3); }

#define COMPUTE(c_, kt_)                                                     \
  { _Pragma("unroll") for (int ks = 0; ks < 4; ++ks) {                       \
      int pg = ((ks * 4 + lq) ^ lr) * 8;                                     \
      s16x8 af0 = *(const s16x8*)&Al[(c_)][ar0 + pg];                        \
      s16x8 af1 = *(const s16x8*)&Al[(c_)][ar1 + pg];                        \
      s16x8 bf[4];                                                           \
      _Pragma("unroll") for (int fn = 0; fn < 4; ++fn)                       \
        bf[fn] = *(const s16x8*)&bb[fn][(kt_) * BKF + ks * 32];              \
      _Pragma("unroll") for (int fn = 0; fn < 4; ++fn) {                     \
        acc[0][fn] = __builtin_amdgcn_mfma_f32_16x16x32_bf16(                \
            __builtin_bit_cast(bf16x8, af0),                                 \
            __builtin_bit_cast(bf16x8, bf[fn]), acc[0][fn], 0, 0, 0);        \
        acc[1][fn] = __builtin_amdgcn_mfma_f32_16x16x32_bf16(                \
            __builtin_bit_cast(bf16x8, af1),                                 \
            __builtin_bit_cast(bf16x8, bf[fn]), acc[1][fn], 0, 0, 0);        \
      } } }

#define BARRIER()                                                            \
  { asm volatile("s_waitcnt lgkmcnt(0)" ::: "memory");                       \
    __builtin_amdgcn_s_barrier(); }

#define BODY(kt_, c_, C0, C1, C2, C3, F0, F1, F2, F3)                        \
  { if ((kt_) + 2 < NST) LOADA(F0, F1, F2, F3, (kt_) + 2);                   \
    COMPUTE(c_, kt_);                                                        \
    if ((kt_) + 1 < NST) {                                                   \
      STAGE((c_) ^ 1, C0, C1, C2, C3);                                       \
      BARRIER();                                                             \
    } }

  // prologue: A(0), A(1) in flight; stage A(0)
  LOADA(rP0, rP1, rP2, rP3, 0);
  LOADA(rQ0, rQ1, rQ2, rQ3, 1);
  STAGE(0, rP0, rP1, rP2, rP3);        // reg-dep vmcnt waits only A(0)
  BARRIER();

#pragma unroll 1
  for (int kt = 0; kt < NST; kt += 2) {
    BODY(kt,     0, rQ0, rQ1, rQ2, rQ3, rP0, rP1, rP2, rP3);
    BODY(kt + 1, 1, rP0, rP1, rP2, rP3, rQ0, rQ1, rQ2, rQ3);
  }
#undef BODY
#undef BARRIER
#undef COMPUTE
#undef STAGE
#undef LOADA

  // ---- epilogue: scatter rows (C/D: col=lane&15, row=(lane>>4)*4+reg) ----
#pragma unroll
  for (int fm = 0; fm < 2; ++fm) {
    int mlb = wm * 32 + fm * 16 + lq * 4;
    int t0 = tgt[mlb + 0], t1 = tgt[mlb + 1], t2 = tgt[mlb + 2], t3 = tgt[mlb + 3];
#pragma unroll
    for (int fn = 0; fn < 4; ++fn) {
      int col = wn * 64 + fn * 16 + lr;
      if (t0 >= 0) out[(size_t)t0 * CCOL + col] = acc[fm][fn][0];
      if (t1 >= 0) out[(size_t)t1 * CCOL + col] = acc[fm][fn][1];
      if (t2 >= 0) out[(size_t)t2 * CCOL + col] = acc[fm][fn][2];
      if (t3 >= 0) out[(size_t)t3 * CCOL + col] = acc[fm][fn][3];
    }
  }
}

extern "C" void kernel_launch(void* const* d_in, const int* in_sizes, int n_in,
                              void* d_out, int out_size, void* d_ws, size_t ws_size,
                              hipStream_t stream) {
  const float* x        = (const float*)d_in[0];
  const float* wts      = (const float*)d_in[1];   // (256,256,8) == row-major (256,2048)
  const int*   children = (const int*)d_in[2];
  float*       out      = (float*)d_out;

  int* wsp    = (int*)d_ws;
  int* cnt    = wsp;                 // 391
  int* boff   = wsp + 512;           // 391
  int* rowof  = wsp + 1024;          // 50000
  int* leafof = wsp + 1024 + GM;     // 50000
  unsigned short* Wb = (unsigned short*)((char*)d_ws + (1 << 20));  // 1 MB bf16 W

  const int nb = (CH_N + 255) / 256;   // 391

  prep_kernel<<<256 + nb, 256, 0, stream>>>(wts, Wb, children, cnt);
  scan_blocks<<<1, 512, 0, stream>>>(cnt, boff, nb);
  rank_kernel<<<nb, 256, 0, stream>>>(children, boff, CH_N, rowof, leafof);

  const float* A = x + (size_t)(PREFIX_N + LEAF_N) * CCOL;
  main_kernel<<<TILES + NCOPYB, 512, 0, stream>>>(x, A, Wb, rowof, leafof, out);
}

// Round 8
// 311.281 us; speedup vs baseline: 1.0483x; 1.0483x over previous
//
#include <hip/hip_runtime.h>
#include <hip/hip_bf16.h>

#define PREFIX_N 20000
#define LEAF_N   50000
#define CH_N     100000
#define CCOL     256
#define GK       2048
#define GM       50000
#define BM       32
#define KH       1024                   /* K floats per half */
#define TILES    ((GM + BM - 1) / BM)   /* 1563 */
#define NCOPYB   512
#define COPYROWS 70000

typedef float  f32x4v __attribute__((ext_vector_type(4)));
typedef __bf16 bf16x8 __attribute__((ext_vector_type(8)));
typedef short  s16x8  __attribute__((ext_vector_type(8)));

static __device__ __forceinline__ unsigned pk2(float a, float b) {
  __hip_bfloat16 ha = __float2bfloat16(a);
  __hip_bfloat16 hb = __float2bfloat16(b);
  unsigned short sa = __builtin_bit_cast(unsigned short, ha);
  unsigned short sb = __builtin_bit_cast(unsigned short, hb);
  return (unsigned)sa | ((unsigned)sb << 16);
}
static __device__ __forceinline__ uint4 pack8(const float4& x, const float4& y) {
  uint4 r;
  r.x = pk2(x.x, x.y); r.y = pk2(x.z, x.w);
  r.z = pk2(y.x, y.y); r.w = pk2(y.z, y.w);
  return r;
}

// ---- prep: W fp32->bf16 (blocks 0..255) + leaf count (blocks 256..646) ---
__global__ __launch_bounds__(256) void prep_kernel(const float* __restrict__ W,
                                                   unsigned short* __restrict__ Wb,
                                                   const int* __restrict__ ch,
                                                   int* __restrict__ cnt) {
  if (blockIdx.x < 256) {
    int i = blockIdx.x * 256 + threadIdx.x;
    float4 a = ((const float4*)W)[i * 2];
    float4 b = ((const float4*)W)[i * 2 + 1];
    *(uint4*)&Wb[i * 8] = pack8(a, b);
  } else {
    int blk = blockIdx.x - 256;
    int gi = blk * 256 + threadIdx.x;
    int lm = (gi < CH_N && ch[gi] < 0) ? 1 : 0;
    unsigned long long mask = __ballot(lm);
    __shared__ int wsum[4];
    int lane = threadIdx.x & 63, w = threadIdx.x >> 6;
    if (lane == 0) wsum[w] = __popcll(mask);
    __syncthreads();
    if (threadIdx.x == 0) cnt[blk] = wsum[0] + wsum[1] + wsum[2] + wsum[3];
  }
}

__global__ __launch_bounds__(512) void scan_blocks(const int* __restrict__ cnt,
                                                   int* __restrict__ boff, int nb) {
  __shared__ int s[512];
  int t = threadIdx.x;
  int v = (t < nb) ? cnt[t] : 0;
  s[t] = v;
  __syncthreads();
  for (int d = 1; d < 512; d <<= 1) {
    int add = (t >= d) ? s[t - d] : 0;
    __syncthreads();
    s[t] += add;
    __syncthreads();
  }
  if (t < nb) boff[t] = s[t] - v;
}

__global__ __launch_bounds__(256) void rank_kernel(const int* __restrict__ ch,
                                                   const int* __restrict__ boff, int n,
                                                   int* __restrict__ rowof,
                                                   int* __restrict__ leafof) {
  int gi = blockIdx.x * 256 + threadIdx.x;
  int lane = threadIdx.x & 63, w = threadIdx.x >> 6;
  int lm = (gi < n && ch[gi] < 0) ? 1 : 0;
  unsigned long long mask = __ballot(lm);
  int lrank = __popcll(mask & ((1ull << lane) - 1ull));
  __shared__ int wcnt[4];
  if (lane == 63) wcnt[w] = lrank + lm;
  __syncthreads();
  int woff = 0;
  for (int i = 0; i < w; ++i) woff += wcnt[i];
  if (gi < n) {
    int rl = boff[blockIdx.x] + woff + lrank;
    if (lm) leafof[rl] = gi;
    else    rowof[gi - rl] = gi;
  }
}

// ---- main: GEMM tiles (blocks < TILES) + grid-stride row copies ----------
// GEMM: BM=32, BN=256(full), K in 2 halves of 1024. Per half: stage phase
// reads 32 rows x 4KB FULLY SEQUENTIALLY (thread t = float4 #t of the row,
// 32-deep ILP), cvt->bf16 into XOR-swizzled LDS; one __syncthreads; compute
// phase (32 ksteps x 8 MFMA/wave) with B direct from L2-resident bf16 W;
// one __syncthreads. 2 blocks/CU: one stages while the other computes.
__global__ __launch_bounds__(256, 2) void main_kernel(const float* __restrict__ x,
                                                      const float* __restrict__ A,
                                                      const unsigned short* __restrict__ Wb,
                                                      const int* __restrict__ rowof,
                                                      const int* __restrict__ leafof,
                                                      float* __restrict__ out) {
  __shared__ unsigned short Al[BM][KH];   // 64KB bf16, 16B-granule XOR swizzle
  __shared__ int tgt[BM];

  const int tid  = threadIdx.x;
  const int lane = tid & 63;
  const int w    = tid >> 6;

  if (blockIdx.x >= TILES) {                      // ---- copy path ----
    int cb = blockIdx.x - TILES;
    for (int r0c = cb * 4; r0c < COPYROWS; r0c += NCOPYB * 4) {
      int j = r0c + w;
      if (j >= COPYROWS) break;
      const float* src;
      float* dst;
      if (j < PREFIX_N) {
        src = x + (size_t)j * CCOL;
        dst = out + (size_t)j * CCOL;
      } else {
        int r = j - PREFIX_N;
        src = x + (size_t)(PREFIX_N + r) * CCOL;
        dst = out + (size_t)(PREFIX_N + leafof[r]) * CCOL;
      }
      ((float4*)dst)[lane] = ((const float4*)src)[lane];
    }
    return;
  }

  // ---- GEMM path ----
  const int tile = blockIdx.x;
  const int wn   = w;                  // wave's N-quadrant
  const int lr   = lane & 15, lq = lane >> 4;

  if (tid < BM) {
    int m = tile * BM + tid;
    tgt[tid] = (m < GM) ? (PREFIX_N + rowof[m]) : -1;
  }

  const size_t r0 = (size_t)tile * BM;
  const float* a0 = A + tid * 4;       // this thread's column slot

  // B fragment base pointers (global; Wb 1MB, L2-resident)
  const unsigned short* bb[4];
#pragma unroll
  for (int fn = 0; fn < 4; ++fn)
    bb[fn] = Wb + (size_t)(wn * 64 + fn * 16 + lr) * GK + lq * 8;

  f32x4v acc[2][4] = {};

  // LDS write slot for (row r): byte = r*2048 + ((g ^ (r&15))<<4) + (tid&1)*8,
  // g = tid>>1  (granule = 16B = 8 bf16)
#define STAGE_BATCH(b2_, h_)                                                 \
  { float4 v_[16];                                                           \
    _Pragma("unroll") for (int i = 0; i < 16; ++i) {                         \
      size_t gr = r0 + (b2_) * 16 + i;                                       \
      if (gr >= GM) gr = GM - 1;                                             \
      v_[i] = *(const float4*)(a0 + (gr << 11) + (h_) * KH);                 \
    }                                                                        \
    _Pragma("unroll") for (int i = 0; i < 16; ++i) {                         \
      int r = (b2_) * 16 + i;                                                \
      uint2 p_; p_.x = pk2(v_[i].x, v_[i].y); p_.y = pk2(v_[i].z, v_[i].w);  \
      *(uint2*)((char*)&Al[r][0] +                                           \
                ((((tid >> 1) ^ (r & 15)) << 4) + ((tid & 1) << 3))) = p_;   \
    } }

#pragma unroll 1
  for (int h = 0; h < 2; ++h) {
    STAGE_BATCH(0, h);
    STAGE_BATCH(1, h);
    __syncthreads();                   // LDS half ready (one drain per phase)

#pragma unroll 8
    for (int ks = 0; ks < KH / 32; ++ks) {
      s16x8 af[2], bf[4];
#pragma unroll
      for (int fm = 0; fm < 2; ++fm)
        af[fm] = *(const s16x8*)((const char*)&Al[fm * 16 + lr][0] +
                                 ((((ks << 2) + lq) ^ lr) << 4));
#pragma unroll
      for (int fn = 0; fn < 4; ++fn)
        bf[fn] = *(const s16x8*)&bb[fn][h * KH + ks * 32];
#pragma unroll
      for (int fm = 0; fm < 2; ++fm)
#pragma unroll
        for (int fn = 0; fn < 4; ++fn)
          acc[fm][fn] = __builtin_amdgcn_mfma_f32_16x16x32_bf16(
              __builtin_bit_cast(bf16x8, af[fm]),
              __builtin_bit_cast(bf16x8, bf[fn]),
              acc[fm][fn], 0, 0, 0);
    }
    __syncthreads();                   // reads done; next half may overwrite
  }
#undef STAGE_BATCH

  // ---- epilogue: scatter rows (C/D: col=lane&15, row=(lane>>4)*4+reg) ----
#pragma unroll
  for (int fm = 0; fm < 2; ++fm) {
    int mlb = fm * 16 + lq * 4;
    int t0 = tgt[mlb + 0], t1 = tgt[mlb + 1], t2 = tgt[mlb + 2], t3 = tgt[mlb + 3];
#pragma unroll
    for (int fn = 0; fn < 4; ++fn) {
      int col = wn * 64 + fn * 16 + lr;
      if (t0 >= 0) out[(size_t)t0 * CCOL + col] = acc[fm][fn][0];
      if (t1 >= 0) out[(size_t)t1 * CCOL + col] = acc[fm][fn][1];
      if (t2 >= 0) out[(size_t)t2 * CCOL + col] = acc[fm][fn][2];
      if (t3 >= 0) out[(size_t)t3 * CCOL + col] = acc[fm][fn][3];
    }
  }
}

extern "C" void kernel_launch(void* const* d_in, const int* in_sizes, int n_in,
                              void* d_out, int out_size, void* d_ws, size_t ws_size,
                              hipStream_t stream) {
  const float* x        = (const float*)d_in[0];
  const float* wts      = (const float*)d_in[1];   // (256,256,8) == row-major (256,2048)
  const int*   children = (const int*)d_in[2];
  float*       out      = (float*)d_out;

  int* wsp    = (int*)d_ws;
  int* cnt    = wsp;                 // 391
  int* boff   = wsp + 512;           // 391
  int* rowof  = wsp + 1024;          // 50000
  int* leafof = wsp + 1024 + GM;     // 50000
  unsigned short* Wb = (unsigned short*)((char*)d_ws + (1 << 20));  // 1 MB bf16 W

  const int nb = (CH_N + 255) / 256;   // 391

  prep_kernel<<<256 + nb, 256, 0, stream>>>(wts, Wb, children, cnt);
  scan_blocks<<<1, 512, 0, stream>>>(cnt, boff, nb);
  rank_kernel<<<nb, 256, 0, stream>>>(children, boff, CH_N, rowof, leafof);

  const float* A = x + (size_t)(PREFIX_N + LEAF_N) * CCOL;
  main_kernel<<<TILES + NCOPYB, 256, 0, stream>>>(x, A, Wb, rowof, leafof, out);
}